// Round 1
// baseline (479.940 us; speedup 1.0000x reference)
//
#include <hip/hip_runtime.h>

#define T_TOK 2048
#define H_DIM 1024
#define E_NUM 16
#define F_DIM 1024
#define NKB 32  // K is tiled in 32 blocks of 32

typedef unsigned short u16;
typedef unsigned int u32;
typedef short s16x8 __attribute__((ext_vector_type(8)));
typedef float f32x4 __attribute__((ext_vector_type(4)));

__device__ __forceinline__ float b2f(u16 v) { return __uint_as_float(((u32)v) << 16); }
__device__ __forceinline__ u16 f2b(float f) {
  u32 u = __float_as_uint(f);
  return (u16)((u + 0x7fffu + ((u >> 16) & 1u)) >> 16);
}

__device__ __forceinline__ void gl_lds16(const u32* g, u32* l) {
  __builtin_amdgcn_global_load_lds((const __attribute__((address_space(1))) void*)g,
                                   (__attribute__((address_space(3))) void*)l, 16, 0, 0);
}

// ---------------- router (fp32): logits, top-2, softmax, counts ----------------
__global__ void router_kernel(const float* __restrict__ hidden, const float* __restrict__ rw,
                              int* __restrict__ counts, int* __restrict__ routing_e,
                              float* __restrict__ routing_w) {
  int t = blockIdx.x;
  int lane = threadIdx.x;  // 64
  const float* xrow = hidden + (size_t)t * H_DIM;
  float acc[E_NUM];
#pragma unroll
  for (int e = 0; e < E_NUM; ++e) acc[e] = 0.f;
  for (int j = 0; j < H_DIM / 64; ++j) {
    int h = j * 64 + lane;
    float x = xrow[h];
    const float* wr = rw + h * E_NUM;
#pragma unroll
    for (int e = 0; e < E_NUM; ++e) acc[e] += x * wr[e];
  }
#pragma unroll
  for (int e = 0; e < E_NUM; ++e) {
    acc[e] += __shfl_xor(acc[e], 32, 64);
    acc[e] += __shfl_xor(acc[e], 16, 64);
    acc[e] += __shfl_xor(acc[e], 8, 64);
    acc[e] += __shfl_xor(acc[e], 4, 64);
    acc[e] += __shfl_xor(acc[e], 2, 64);
    acc[e] += __shfl_xor(acc[e], 1, 64);
  }
  if (lane == 0) {
    float v0 = -1e30f, v1 = -1e30f;
    int i0 = 0, i1 = 0;
#pragma unroll
    for (int e = 0; e < E_NUM; ++e) {
      float v = acc[e];
      if (v > v0) { v1 = v0; i1 = i0; v0 = v; i0 = e; }
      else if (v > v1) { v1 = v; i1 = e; }
    }
    float p0 = 1.f / (1.f + __expf(v1 - v0));  // stable: v1 <= v0
    routing_e[2 * t] = i0;
    routing_e[2 * t + 1] = i1;
    routing_w[2 * t] = p0;
    routing_w[2 * t + 1] = 1.f - p0;
    atomicAdd(&counts[i0], 1);
    atomicAdd(&counts[i1], 1);
  }
}

// ---------------- scatter: prefix offsets + slot maps + per-slot weight ----------------
__global__ void scatter_kernel(const int* __restrict__ counts, int* __restrict__ offsets,
                               const int* __restrict__ routing_e, const float* __restrict__ routing_w,
                               int* __restrict__ token_of_slot, float* __restrict__ slot_w) {
  __shared__ int offs[E_NUM];
  __shared__ int cur[E_NUM];
  int tid = threadIdx.x;
  if (tid == 0) {
    int s = 0;
    for (int e = 0; e < E_NUM; ++e) { offs[e] = s; s += counts[e]; }
  }
  __syncthreads();
  if (tid < E_NUM) { offsets[tid] = offs[tid]; cur[tid] = offs[tid]; }
  __syncthreads();
  for (int i = tid; i < 2 * T_TOK; i += 256) {
    int e = routing_e[i];
    int pos = atomicAdd(&cur[e], 1);
    token_of_slot[pos] = i >> 1;
    slot_w[pos] = routing_w[i];
  }
}

// split 8 fp32 -> bf16 hi + bf16 lo(residual), packed for b128 store
__device__ __forceinline__ void split_pack(const float* __restrict__ p, uint4& hh, uint4& ll) {
  u16 h[8], l[8];
#pragma unroll
  for (int i = 0; i < 8; ++i) {
    h[i] = f2b(p[i]);
    l[i] = f2b(p[i] - b2f(h[i]));
  }
  hh.x = (u32)h[0] | ((u32)h[1] << 16);
  hh.y = (u32)h[2] | ((u32)h[3] << 16);
  hh.z = (u32)h[4] | ((u32)h[5] << 16);
  hh.w = (u32)h[6] | ((u32)h[7] << 16);
  ll.x = (u32)l[0] | ((u32)l[1] << 16);
  ll.y = (u32)l[2] | ((u32)l[3] << 16);
  ll.z = (u32)l[4] | ((u32)l[5] << 16);
  ll.w = (u32)l[6] | ((u32)l[7] << 16);
}

// ---------------- prep_x: hidden f32 -> bf16 hi/lo planes ----------------
__global__ __launch_bounds__(256) void prep_x(const float* __restrict__ x, u16* __restrict__ xh,
                                              u16* __restrict__ xl) {
  int i = blockIdx.x * 256 + threadIdx.x;  // 8 elems per thread, exact grid
  float4 a = ((const float4*)x)[2 * i];
  float4 b = ((const float4*)x)[2 * i + 1];
  float v[8] = {a.x, a.y, a.z, a.w, b.x, b.y, b.z, b.w};
  uint4 hh, ll;
  split_pack(v, hh, ll);
  ((uint4*)xh)[i] = hh;
  ((uint4*)xl)[i] = ll;
}

// ---------------- prep_w: f32 [1024][N] -> bf16 swizzled 8KB LDS-image tiles ----------------
// tile(e, nblk, kblk) = [n 0..127][16 u32 words], word pos = ((g0^(n>>3)^n)&3)*4 + w,
// word = bf16(k=2kp)|bf16(k=2kp+1)<<16 with kp = g0*4 + w  (identical to read_bfrag layout)
__global__ __launch_bounds__(256) void prep_w(const float* __restrict__ w, u32* __restrict__ wt,
                                              int N) {
  const int e = blockIdx.z, nbk = blockIdx.y, kb = blockIdx.x;
  const float* src = w + (size_t)e * 1024 * N + (size_t)kb * 32 * N + nbk * 128;
  u32* dst = wt + (((size_t)e * gridDim.y + nbk) * NKB + kb) * 2048;
  __shared__ u16 L[32][132];
  const int t = threadIdx.x;
  const int kr = t >> 5;
  const int nq = (t & 31) * 4;
#pragma unroll
  for (int p = 0; p < 4; ++p) {
    int k = p * 8 + kr;
    float4 v = *(const float4*)(src + (size_t)k * N + nq);
    L[k][nq] = f2b(v.x);
    L[k][nq + 1] = f2b(v.y);
    L[k][nq + 2] = f2b(v.z);
    L[k][nq + 3] = f2b(v.w);
  }
  __syncthreads();
  const int n = t >> 1, half = t & 1;
  const int s = ((n >> 3) ^ n) & 3;
  __align__(16) u32 buf[8];
#pragma unroll
  for (int j = 0; j < 8; ++j) {
    int pos = half * 8 + j;
    int g0 = ((pos >> 2) ^ s) & 3;
    int kp = g0 * 4 + (pos & 3);
    buf[j] = (u32)L[2 * kp][n] | ((u32)L[2 * kp + 1][n] << 16);
  }
  *(uint4*)(dst + n * 16 + half * 8) = *(uint4*)&buf[0];
  *(uint4*)(dst + n * 16 + half * 8 + 4) = *(uint4*)&buf[4];
}

__device__ __forceinline__ s16x8 read_bfrag(const u32* __restrict__ B, int n, int q) {
  return *(const s16x8*)&B[n * 16 + (((q ^ (n >> 3) ^ n) & 3) << 2)];
}

#define MFMA(a, b, c) __builtin_amdgcn_mfma_f32_16x16x32_bf16(a, b, c, 0, 0, 0)

// ---------------- GEMM1: act = silu(X@Wg)*(X@Wu), A direct-from-global, W via gload_lds ----------------
__global__ __launch_bounds__(256, 2) void moe_gemm1(
    const u16* __restrict__ Xh, const u16* __restrict__ Xl, const u32* __restrict__ wgu_t,
    const int* __restrict__ token_of_slot, const int* __restrict__ counts,
    const int* __restrict__ offsets, u16* __restrict__ act_h, u16* __restrict__ act_l) {
  const int e = blockIdx.z;
  const int cnt = counts[e];
  const int m0 = blockIdx.y * 64;
  if (m0 >= cnt) return;
  const int off = offsets[e];
  const int xb = blockIdx.x;

  __shared__ u32 Bg[2][2048];
  __shared__ u32 Bu[2][2048];

  const int tid = threadIdx.x;
  const int lane = tid & 63;
  const int wv = tid >> 6;
  const int q = lane >> 4, ln = lane & 15;
  const int mb = (wv & 1) * 32, nb = (wv >> 1) * 64;

  const int r0 = m0 + mb + ln, r1 = r0 + 16;
  const int t0 = (r0 < cnt) ? token_of_slot[off + r0] : 0;
  const int t1 = (r1 < cnt) ? token_of_slot[off + r1] : 0;
  const u16* xh0 = Xh + (size_t)t0 * H_DIM + q * 8;
  const u16* xh1 = Xh + (size_t)t1 * H_DIM + q * 8;
  const u16* xl0 = Xl + (size_t)t0 * H_DIM + q * 8;
  const u16* xl1 = Xl + (size_t)t1 * H_DIM + q * 8;

  const u32* g_g = wgu_t + (((size_t)e * 16 + xb) * NKB) * 2048 + tid * 4;
  const u32* g_u = wgu_t + (((size_t)e * 16 + xb + 8) * NKB) * 2048 + tid * 4;

  f32x4 zero = {0.f, 0.f, 0.f, 0.f};
  f32x4 accg[2][4], accu[2][4];
#pragma unroll
  for (int i = 0; i < 2; ++i)
#pragma unroll
    for (int j = 0; j < 4; ++j) { accg[i][j] = zero; accu[i][j] = zero; }

#define STAGE1(kbn, LG, LU)                          \
  {                                                  \
    const u32* sg = g_g + (size_t)(kbn) * 2048;      \
    const u32* su = g_u + (size_t)(kbn) * 2048;      \
    gl_lds16(sg, (LG) + wv * 256);                   \
    gl_lds16(sg + 1024, (LG) + 1024 + wv * 256);     \
    gl_lds16(su, (LU) + wv * 256);                   \
    gl_lds16(su + 1024, (LU) + 1024 + wv * 256);     \
  }

  STAGE1(0, &Bg[0][0], &Bu[0][0]);
  __syncthreads();

#define G1BODY(kb, CG, CU, NG, NU)                               \
  {                                                              \
    const int koff = (kb) * 32;                                  \
    s16x8 ah0 = *(const s16x8*)(xh0 + koff);                     \
    s16x8 ah1 = *(const s16x8*)(xh1 + koff);                     \
    s16x8 al0 = *(const s16x8*)(xl0 + koff);                     \
    s16x8 al1 = *(const s16x8*)(xl1 + koff);                     \
    if ((kb) + 1 < NKB) STAGE1((kb) + 1, NG, NU);                \
    _Pragma("unroll")                                            \
    for (int j = 0; j < 4; ++j) {                                \
      s16x8 bg = read_bfrag(CG, nb + j * 16 + ln, q);            \
      s16x8 bu = read_bfrag(CU, nb + j * 16 + ln, q);            \
      accg[0][j] = MFMA(ah0, bg, accg[0][j]);                    \
      accg[1][j] = MFMA(ah1, bg, accg[1][j]);                    \
      accu[0][j] = MFMA(ah0, bu, accu[0][j]);                    \
      accu[1][j] = MFMA(ah1, bu, accu[1][j]);                    \
      accg[0][j] = MFMA(al0, bg, accg[0][j]);                    \
      accg[1][j] = MFMA(al1, bg, accg[1][j]);                    \
      accu[0][j] = MFMA(al0, bu, accu[0][j]);                    \
      accu[1][j] = MFMA(al1, bu, accu[1][j]);                    \
    }                                                            \
    __syncthreads();                                             \
  }

  for (int kb = 0; kb < NKB; kb += 2) {
    G1BODY(kb, &Bg[0][0], &Bu[0][0], &Bg[1][0], &Bu[1][0]);
    G1BODY(kb + 1, &Bg[1][0], &Bu[1][0], &Bg[0][0], &Bu[0][0]);
  }

  const int bcol = xb * 128 + nb + ln;
#pragma unroll
  for (int i = 0; i < 2; ++i) {
#pragma unroll
    for (int r = 0; r < 4; ++r) {
      int row = mb + i * 16 + q * 4 + r;
      if (m0 + row < cnt) {
        size_t rb = (size_t)(off + m0 + row) * F_DIM + bcol;
#pragma unroll
        for (int j = 0; j < 4; ++j) {
          float g = accg[i][j][r], u = accu[i][j][r];
          float a = g * (1.f / (1.f + __expf(-g))) * u;
          u16 h = f2b(a);
          u16 l = f2b(a - b2f(h));
          act_h[rb + j * 16] = h;
          act_l[rb + j * 16] = l;
        }
      }
    }
  }
}

// ---------------- GEMM2: out[tok,h] += w_slot * (act @ w_down)  (atomic fp32) ----------------
__global__ __launch_bounds__(256, 2) void moe_gemm2(
    const u16* __restrict__ Ah, const u16* __restrict__ Al, const u32* __restrict__ wd_t,
    const int* __restrict__ token_of_slot, const float* __restrict__ slot_w,
    const int* __restrict__ counts, const int* __restrict__ offsets,
    float* __restrict__ out) {
  const int e = blockIdx.z;
  const int cnt = counts[e];
  const int m0 = blockIdx.y * 64;
  if (m0 >= cnt) return;
  const int off = offsets[e];
  const int xb = blockIdx.x;

  __shared__ u32 Bd[2][2048];

  const int tid = threadIdx.x;
  const int lane = tid & 63;
  const int wv = tid >> 6;
  const int q = lane >> 4, ln = lane & 15;
  const int mb = (wv & 1) * 32, nb = (wv >> 1) * 64;

  const int r0 = m0 + mb + ln, r1 = r0 + 16;
  const int s0 = off + ((r0 < cnt) ? r0 : 0);
  const int s1 = off + ((r1 < cnt) ? r1 : 0);
  const u16* ah0 = Ah + (size_t)s0 * F_DIM + q * 8;
  const u16* ah1 = Ah + (size_t)s1 * F_DIM + q * 8;
  const u16* al0 = Al + (size_t)s0 * F_DIM + q * 8;
  const u16* al1 = Al + (size_t)s1 * F_DIM + q * 8;

  const u32* g_d = wd_t + (((size_t)e * 8 + xb) * NKB) * 2048 + tid * 4;

  f32x4 zero = {0.f, 0.f, 0.f, 0.f};
  f32x4 acc[2][4];
#pragma unroll
  for (int i = 0; i < 2; ++i)
#pragma unroll
    for (int j = 0; j < 4; ++j) acc[i][j] = zero;

#define STAGE2(kbn, LD)                              \
  {                                                  \
    const u32* sd = g_d + (size_t)(kbn) * 2048;      \
    gl_lds16(sd, (LD) + wv * 256);                   \
    gl_lds16(sd + 1024, (LD) + 1024 + wv * 256);     \
  }

  STAGE2(0, &Bd[0][0]);
  __syncthreads();

#define G2BODY(kb, CD, ND)                               \
  {                                                      \
    const int koff = (kb) * 32;                          \
    s16x8 a0 = *(const s16x8*)(ah0 + koff);              \
    s16x8 a1 = *(const s16x8*)(ah1 + koff);              \
    s16x8 b0 = *(const s16x8*)(al0 + koff);              \
    s16x8 b1 = *(const s16x8*)(al1 + koff);              \
    if ((kb) + 1 < NKB) STAGE2((kb) + 1, ND);            \
    _Pragma("unroll")                                    \
    for (int j = 0; j < 4; ++j) {                        \
      s16x8 bf = read_bfrag(CD, nb + j * 16 + ln, q);    \
      acc[0][j] = MFMA(a0, bf, acc[0][j]);               \
      acc[1][j] = MFMA(a1, bf, acc[1][j]);               \
      acc[0][j] = MFMA(b0, bf, acc[0][j]);               \
      acc[1][j] = MFMA(b1, bf, acc[1][j]);               \
    }                                                    \
    __syncthreads();                                     \
  }

  for (int kb = 0; kb < NKB; kb += 2) {
    G2BODY(kb, &Bd[0][0], &Bd[1][0]);
    G2BODY(kb + 1, &Bd[1][0], &Bd[0][0]);
  }

#pragma unroll
  for (int i = 0; i < 2; ++i) {
#pragma unroll
    for (int r = 0; r < 4; ++r) {
      int row = mb + i * 16 + q * 4 + r;
      if (m0 + row < cnt) {
        int slot = off + m0 + row;
        int tok = token_of_slot[slot];
        float wgt = slot_w[slot];
        float* orow = out + (size_t)tok * H_DIM + xb * 128 + nb + ln;
#pragma unroll
        for (int j = 0; j < 4; ++j) atomicAdd(&orow[j * 16], wgt * acc[i][j][r]);
      }
    }
  }
}

extern "C" void kernel_launch(void* const* d_in, const int* in_sizes, int n_in,
                              void* d_out, int out_size, void* d_ws, size_t ws_size,
                              hipStream_t stream) {
  const float* hidden = (const float*)d_in[0];  // [2048][1024] f32
  const float* rw = (const float*)d_in[1];      // [1024][16]   f32
  const float* wgu = (const float*)d_in[2];     // [16][1024][2048] f32
  const float* wd = (const float*)d_in[3];      // [16][1024][1024] f32
  float* out = (float*)d_out;                   // [2048][1024] f32
  char* ws = (char*)d_ws;

  // workspace layout (~126 MB)
  int* counts = (int*)(ws);                        // 64 B
  int* offsets = (int*)(ws + 256);                 // 64 B
  int* routing_e = (int*)(ws + 1024);              // 16 KB
  float* routing_w = (float*)(ws + 17408);         // 16 KB
  int* token_of_slot = (int*)(ws + 33792);         // 16 KB
  float* slot_w = (float*)(ws + 50176);            // 16 KB
  u16* Xh = (u16*)(ws + 131072ull);                // 4 MB  [2048][1024] bf16 hi
  u16* Xl = (u16*)(ws + 4325376ull);               // 4 MB  bf16 lo residual
  u16* act_h = (u16*)(ws + 8519680ull);            // 8 MB  [4096][1024] bf16 hi
  u16* act_l = (u16*)(ws + 16908288ull);           // 8 MB  bf16 lo residual
  u32* wgu_t = (u32*)(ws + 25296896ull);           // 64 MB swizzled bf16 tiles
  u32* wd_t  = (u32*)(ws + 92405760ull);           // 32 MB swizzled bf16 tiles

  hipMemsetAsync(counts, 0, 64, stream);
  hipMemsetAsync(out, 0, (size_t)out_size * sizeof(float), stream);
  router_kernel<<<dim3(T_TOK), dim3(64), 0, stream>>>(hidden, rw, counts, routing_e, routing_w);
  scatter_kernel<<<dim3(1), dim3(256), 0, stream>>>(counts, offsets, routing_e, routing_w,
                                                    token_of_slot, slot_w);
  prep_x<<<dim3(T_TOK * H_DIM / 8 / 256), dim3(256), 0, stream>>>(hidden, Xh, Xl);
  prep_w<<<dim3(NKB, 16, E_NUM), dim3(256), 0, stream>>>(wgu, wgu_t, 2048);
  prep_w<<<dim3(NKB, 8, E_NUM), dim3(256), 0, stream>>>(wd, wd_t, 1024);
  moe_gemm1<<<dim3(8, 32, E_NUM), dim3(256), 0, stream>>>(Xh, Xl, wgu_t, token_of_slot, counts,
                                                          offsets, act_h, act_l);
  moe_gemm2<<<dim3(8, 32, E_NUM), dim3(256), 0, stream>>>(act_h, act_l, wd_t, token_of_slot,
                                                          slot_w, counts, offsets, out);
}